// Round 4
// baseline (87.958 us; speedup 1.0000x reference)
//
#include <hip/hip_runtime.h>
#include <hip/hip_bf16.h>
#include <stdint.h>

// out[b,i] = sum_{j,l} x[b,j,l] * k[i,j] * conj(k[i,l]),  x = R + iM, k = p + iq
// Step 1 (MFMA): T = X_b * K^H  (A-operand = X rows -> contiguous global loads)
//   T_re = R*P^T + M*Q^T ; T_im = M*P^T - R*Q^T   (B-frag [l][i] read from LDS [i][l])
// Step 2 (epilogue): out_re = sum_j T_re*p[i,j] - T_im*q[i,j]
//   -> k[i,j] weights now loaded from GLOBAL as float2 (f32 precision, and
//      removes the swizzled-LDS epilogue read path entirely).
// d_out = float32[B*E] = Re(out) (round-3 finding). Writes guarded by nout.

typedef __attribute__((ext_vector_type(8))) __bf16 bf16x8;
typedef __attribute__((ext_vector_type(4))) float f32x4;
typedef __attribute__((ext_vector_type(4))) unsigned int u32x4;

#define EDIM 128

static __device__ inline bf16x8 neg8(bf16x8 v) {
    u32x4 u = __builtin_bit_cast(u32x4, v);
    u ^= (u32x4){0x80008000u, 0x80008000u, 0x80008000u, 0x80008000u};
    return __builtin_bit_cast(bf16x8, u);
}

__global__ __launch_bounds__(512, 4) void qmeas_kernel(
    const float* __restrict__ R, const float* __restrict__ M,
    const float* __restrict__ Kern, float* __restrict__ out, int nout)
{
    __shared__ __align__(16) unsigned char smem[65536];

    const int t    = threadIdx.x;
    const int lane = t & 63;
    const int w    = t >> 6;       // wave 0..7
    const int li   = lane & 15;
    const int s    = lane >> 4;    // 0..3
    const int b    = blockIdx.x;

    // ---- stage kernel (f32 interleaved p,q -> bf16 Pb/Qb, XOR-swizzled) ----
    for (int it = 0; it < 4; ++it) {
        int idx = t + it * 512;            // 0..2047
        int i   = idx >> 4;                // row 0..127
        int l0  = (idx & 15) << 3;         // 0,8,...,120
        const float* g = Kern + (((size_t)i * EDIM + l0) << 1);
        f32x4 f0 = *(const f32x4*)(g);
        f32x4 f1 = *(const f32x4*)(g + 4);
        f32x4 f2 = *(const f32x4*)(g + 8);
        f32x4 f3 = *(const f32x4*)(g + 12);
        bf16x8 pv, qv;
        pv[0] = (__bf16)f0[0]; qv[0] = (__bf16)f0[1];
        pv[1] = (__bf16)f0[2]; qv[1] = (__bf16)f0[3];
        pv[2] = (__bf16)f1[0]; qv[2] = (__bf16)f1[1];
        pv[3] = (__bf16)f1[2]; qv[3] = (__bf16)f1[3];
        pv[4] = (__bf16)f2[0]; qv[4] = (__bf16)f2[1];
        pv[5] = (__bf16)f2[2]; qv[5] = (__bf16)f2[3];
        pv[6] = (__bf16)f3[0]; qv[6] = (__bf16)f3[1];
        pv[7] = (__bf16)f3[2]; qv[7] = (__bf16)f3[3];
        int off = (i * 256 + (l0 << 1)) ^ ((i & 7) << 4);
        *(bf16x8*)(smem + off)         = pv;   // Pb
        *(bf16x8*)(smem + 32768 + off) = qv;   // Qb
    }
    __syncthreads();

    // ---- main loop: T tile [16 j-rows of this wave] x [128 i] ----
    f32x4 acc_re[8], acc_im[8];
#pragma unroll
    for (int n = 0; n < 8; ++n) {
        acc_re[n] = (f32x4){0.f, 0.f, 0.f, 0.f};
        acc_im[n] = (f32x4){0.f, 0.f, 0.f, 0.f};
    }

    const int    j     = (w << 4) + li;                       // this lane's A-row
    const size_t xbase = (size_t)b * (EDIM * EDIM) + (size_t)j * EDIM;

#pragma unroll
    for (int kT = 0; kT < 4; ++kT) {
        const int l0 = kT * 32 + s * 8;
        f32x4 rf0 = *(const f32x4*)(R + xbase + l0);
        f32x4 rf1 = *(const f32x4*)(R + xbase + l0 + 4);
        f32x4 mf0 = *(const f32x4*)(M + xbase + l0);
        f32x4 mf1 = *(const f32x4*)(M + xbase + l0 + 4);
        bf16x8 ra, ma;
#pragma unroll
        for (int e = 0; e < 4; ++e) {
            ra[e]     = (__bf16)rf0[e];
            ra[4 + e] = (__bf16)rf1[e];
            ma[e]     = (__bf16)mf0[e];
            ma[4 + e] = (__bf16)mf1[e];
        }
        bf16x8 rn = neg8(ra);
        const int lbyte = (l0 << 1);   // byte offset of l0 within a 256B LDS row
#pragma unroll
        for (int nT = 0; nT < 8; ++nT) {
            int i   = (nT << 4) + li;
            int off = ((i << 8) + lbyte) ^ ((li & 7) << 4);
            bf16x8 pB = *(const bf16x8*)(smem + off);
            bf16x8 qB = *(const bf16x8*)(smem + 32768 + off);
            acc_re[nT] = __builtin_amdgcn_mfma_f32_16x16x32_bf16(ra, pB, acc_re[nT], 0, 0, 0);
            acc_re[nT] = __builtin_amdgcn_mfma_f32_16x16x32_bf16(ma, qB, acc_re[nT], 0, 0, 0);
            acc_im[nT] = __builtin_amdgcn_mfma_f32_16x16x32_bf16(ma, pB, acc_im[nT], 0, 0, 0);
            acc_im[nT] = __builtin_amdgcn_mfma_f32_16x16x32_bf16(rn, qB, acc_im[nT], 0, 0, 0);
        }
    }

    // ---- epilogue: weight by k[i,j] from GLOBAL (f32), reduce over j ----
    // D layout: col i-offset = lane&15, row j-offset = (lane>>4)*4 + reg
    const int jrow0 = (w << 4) + (s << 2);   // first of this lane's 4 j-rows
    const float2* K2 = (const float2*)Kern;  // K2[i*128+j] = (p[i][j], q[i][j])
    float re8[8], im8[8];
#pragma unroll
    for (int nT = 0; nT < 8; ++nT) {
        int i = (nT << 4) + li;
        float re = 0.f, im = 0.f;
#pragma unroll
        for (int r = 0; r < 4; ++r) {
            float2 kv = K2[(size_t)i * EDIM + jrow0 + r];
            float tr = acc_re[nT][r], ti = acc_im[nT][r];
            re += tr * kv.x - ti * kv.y;
            im += tr * kv.y + ti * kv.x;
        }
        re += __shfl_xor(re, 16); im += __shfl_xor(im, 16);
        re += __shfl_xor(re, 32); im += __shfl_xor(im, 32);
        re8[nT] = re; im8[nT] = im;
    }

    // ---- reuse smem[0,8192) as float2 part[8][128] (after barrier) ----
    __syncthreads();
    float2* part = (float2*)smem;
    if (s == 0) {
#pragma unroll
        for (int nT = 0; nT < 8; ++nT) {
            int i = (nT << 4) + li;
            part[w * EDIM + i] = make_float2(re8[nT], im8[nT]);
        }
    }
    __syncthreads();

    // ---- cross-wave reduce + store (REAL PART ONLY, guarded by nout) ----
    if (t < EDIM) {
        float2 acc = part[t];
#pragma unroll
        for (int ww = 1; ww < 8; ++ww) {
            float2 v = part[ww * EDIM + t];
            acc.x += v.x;
            acc.y += v.y;
        }
        int oi = b * EDIM + t;
        if (oi < nout) out[oi] = acc.x;
    }
}

extern "C" void kernel_launch(void* const* d_in, const int* in_sizes, int n_in,
                              void* d_out, int out_size, void* d_ws, size_t ws_size,
                              hipStream_t stream) {
    const float* R    = (const float*)d_in[0];
    const float* M    = (const float*)d_in[1];
    const float* Kern = (const float*)d_in[2];
    float*       out  = (float*)d_out;
    const int    B    = in_sizes[0] / (EDIM * EDIM);   // 2048
    qmeas_kernel<<<B, 512, 0, stream>>>(R, M, Kern, out, out_size);
}